// Round 1
// baseline (636.372 us; speedup 1.0000x reference)
//
#include <hip/hip_runtime.h>

typedef __bf16 bf16_t;
typedef bf16_t bf16x4v __attribute__((ext_vector_type(4)));
typedef bf16_t bf16x8v __attribute__((ext_vector_type(8)));
typedef float f32x4 __attribute__((ext_vector_type(4)));

// async global->LDS, 16B per lane (guide §5: dest = wave-uniform base + lane*16)
__device__ __forceinline__ void gl_lds16(const void* g, void* l) {
  __builtin_amdgcn_global_load_lds((__attribute__((address_space(1))) void*)g,
                                   (__attribute__((address_space(3))) void*)l,
                                   16, 0, 0);
}

__device__ __forceinline__ float fast_silu(float x) {
  return x / (1.f + __expf(-x));
}

// ---------------- f32 -> bf16 conversion (vectorized, grid-stride) ----------------
__global__ void cvt_f32_bf16_kernel(const float* __restrict__ in,
                                    bf16_t* __restrict__ out, int n4) {
  int i = blockIdx.x * blockDim.x + threadIdx.x;
  const int stride = gridDim.x * blockDim.x;
  const float4* in4 = (const float4*)in;
  bf16x4v* out4 = (bf16x4v*)out;
  for (; i < n4; i += stride) {
    float4 v = in4[i];
    bf16x4v o;
    o[0] = (bf16_t)v.x; o[1] = (bf16_t)v.y; o[2] = (bf16_t)v.z; o[3] = (bf16_t)v.w;
    out4[i] = o;
  }
}

// ---------------- router: logits, softmax, top-4, expert lists, shared gate ----------------
__global__ __launch_bounds__(256)
void router_kernel(const float* __restrict__ h, const float* __restrict__ rw,
                   const float* __restrict__ segw, float* __restrict__ gsig,
                   int* __restrict__ cnt, int* __restrict__ toklist,
                   float* __restrict__ wlist) {
  const int n = blockIdx.x;
  const int t = threadIdx.x;
  const float* hp = h + (size_t)n * 1024;
  __shared__ float logits[16];
  __shared__ float gred[4];

  // 16 threads per expert, coalesced within 16-lane groups
  const int e = t >> 4;
  const int part = t & 15;
  const float* wrow = rw + (size_t)e * 1024;
  float s = 0.f;
  #pragma unroll 4
  for (int i = 0; i < 64; ++i) {
    int k = i * 16 + part;
    s += hp[k] * wrow[k];
  }
  #pragma unroll
  for (int m = 8; m >= 1; m >>= 1) s += __shfl_xor(s, m);
  if (part == 0) logits[e] = s;

  // shared-expert gate logit: all 256 threads
  float sg = 0.f;
  #pragma unroll
  for (int i = 0; i < 4; ++i) {
    int k = i * 256 + t;
    sg += hp[k] * segw[k];
  }
  #pragma unroll
  for (int m = 32; m >= 1; m >>= 1) sg += __shfl_xor(sg, m);
  if ((t & 63) == 0) gred[t >> 6] = sg;
  __syncthreads();

  if (t == 0) {
    float g = gred[0] + gred[1] + gred[2] + gred[3];
    gsig[n] = 1.f / (1.f + expf(-g));

    float mx = logits[0];
    #pragma unroll
    for (int i = 1; i < 16; ++i) mx = fmaxf(mx, logits[i]);
    float p[16];
    #pragma unroll
    for (int i = 0; i < 16; ++i) p[i] = expf(logits[i] - mx);
    float tv[4]; int ti[4]; float tsum = 0.f;
    for (int k = 0; k < 4; ++k) {
      float bv = -1.f; int bi = 0;
      #pragma unroll
      for (int i = 0; i < 16; ++i) { if (p[i] > bv) { bv = p[i]; bi = i; } }
      p[bi] = -2.f;
      tv[k] = bv; ti[k] = bi; tsum += bv;
    }
    float inv = 1.f / tsum;  // softmax denominator cancels in renormalization
    for (int k = 0; k < 4; ++k) {
      int idx = atomicAdd(&cnt[ti[k]], 1);
      toklist[ti[k] * 4096 + idx] = n;
      wlist[ti[k] * 4096 + idx] = tv[k] * inv;
    }
  }
}

// prefix over 16 counts + constant aux loss (== E exactly, see analysis)
__global__ void finalize_router_kernel(const int* __restrict__ cnt,
                                       int* __restrict__ baseOff,
                                       float* __restrict__ aux) {
  if (threadIdx.x == 0 && blockIdx.x == 0) {
    int s = 0;
    for (int e = 0; e < 16; ++e) { baseOff[e] = s; s += cnt[e]; }
    aux[0] = 16.0f;
  }
}

// ---------------- fused gate/up GEMM: act = silu(A@B1^T) * (A@B2^T) ----------------
// B tile interleaves gate(even n)/up(odd n) rows so the epilogue pairs via shfl_xor(1).
// GATHER: A rows indirected through per-expert token list (grouped GEMM).
template<bool GATHER>
__global__ __launch_bounds__(256, 2)
void gateup_gemm_kernel(const bf16_t* __restrict__ A,
                        const bf16_t* __restrict__ B1,
                        const bf16_t* __restrict__ B2,
                        size_t strideBe,
                        bf16_t* __restrict__ actOut, int ldAct,
                        int K, int Mfixed,
                        const int* __restrict__ cnt,
                        const int* __restrict__ baseOff,
                        const int* __restrict__ toklist) {
  const int e = blockIdx.z;
  const int rowBlk = blockIdx.y, colBlk = blockIdx.x;
  int M, actRowBase;
  if constexpr (GATHER) {
    M = cnt[e];
    if (rowBlk * 128 >= M) return;
    actRowBase = baseOff[e] + rowBlk * 128;
  } else {
    M = Mfixed;
    actRowBase = rowBlk * 128;
  }
  const bf16_t* b1 = B1 + (size_t)e * strideBe;
  const bf16_t* b2 = B2 + (size_t)e * strideBe;

  __shared__ __align__(16) bf16_t As[128 * 64];
  __shared__ __align__(16) bf16_t Bs[128 * 64];

  const int t = threadIdx.x;

  const bf16_t* aSrc[4];
  const bf16_t* bSrc[4];
  #pragma unroll
  for (int i = 0; i < 4; ++i) {
    int r = (t >> 3) + 32 * i;  // tile row 0..127
    int grow;
    if constexpr (GATHER) {
      int rr = rowBlk * 128 + r;
      grow = (rr < M) ? toklist[e * 4096 + rr] : 0;
    } else {
      grow = rowBlk * 128 + r;
    }
    aSrc[i] = A + (size_t)grow * K + (t & 7) * 8;
    int j = colBlk * 64 + (r >> 1);
    bSrc[i] = ((r & 1) ? b2 : b1) + (size_t)j * K + (t & 7) * 8;
  }

  f32x4 acc[4][4];
  #pragma unroll
  for (int a = 0; a < 4; ++a)
    #pragma unroll
    for (int b = 0; b < 4; ++b)
      acc[a][b] = (f32x4){0.f, 0.f, 0.f, 0.f};

  const int lane = t & 63;
  const int wid = t >> 6;
  const int wm = wid >> 1, wn = wid & 1;
  const int lr = lane & 15;
  const int lk = (lane >> 4) * 8;

  bf16_t* aDst = As + t * 8;
  bf16_t* bDst = Bs + t * 8;

  for (int k0 = 0; k0 < K; k0 += 64) {
    #pragma unroll
    for (int i = 0; i < 4; ++i) gl_lds16(aSrc[i], aDst + i * 2048);
    #pragma unroll
    for (int i = 0; i < 4; ++i) gl_lds16(bSrc[i], bDst + i * 2048);
    #pragma unroll
    for (int i = 0; i < 4; ++i) { aSrc[i] += 64; bSrc[i] += 64; }
    __syncthreads();
    #pragma unroll
    for (int kk = 0; kk < 64; kk += 32) {
      bf16x8v af[4], bfr[4];
      #pragma unroll
      for (int f = 0; f < 4; ++f)
        af[f] = *(const bf16x8v*)&As[(wm * 64 + f * 16 + lr) * 64 + kk + lk];
      #pragma unroll
      for (int f = 0; f < 4; ++f)
        bfr[f] = *(const bf16x8v*)&Bs[(wn * 64 + f * 16 + lr) * 64 + kk + lk];
      #pragma unroll
      for (int fm = 0; fm < 4; ++fm)
        #pragma unroll
        for (int fn = 0; fn < 4; ++fn)
          acc[fm][fn] = __builtin_amdgcn_mfma_f32_16x16x32_bf16(
              af[fm], bfr[fn], acc[fm][fn], 0, 0, 0);
    }
    __syncthreads();
  }

  // epilogue: pair gate (even n) with up (odd n) via lane^1, write silu(g)*u
  const int mRem = M - rowBlk * 128;
  #pragma unroll
  for (int fm = 0; fm < 4; ++fm) {
    #pragma unroll
    for (int fn = 0; fn < 4; ++fn) {
      const int nloc = wn * 64 + fn * 16 + lr;
      const int j = colBlk * 64 + (nloc >> 1);
      const bool even = (nloc & 1) == 0;
      #pragma unroll
      for (int r = 0; r < 4; ++r) {
        float mine = acc[fm][fn][r];
        float other = __shfl_xor(mine, 1);
        float gate = even ? mine : other;
        float up = even ? other : mine;
        float act = fast_silu(gate) * up;
        int tr = wm * 64 + fm * 16 + (lane >> 4) * 4 + r;
        if (even && tr < mRem)
          actOut[(size_t)(actRowBase + tr) * ldAct + j] = (bf16_t)act;
      }
    }
  }
}

// ---------------- down GEMM: out (+)= scale * (A @ B^T) ----------------
// EXPERT: scatter rows to tokens with atomicAdd * top-k weight.
// else:   direct store * sigmoid gate (runs first, so adds are ordered after).
template<bool EXPERT>
__global__ __launch_bounds__(256, 2)
void down_gemm_kernel(const bf16_t* __restrict__ Abase,
                      const bf16_t* __restrict__ Bbase,
                      size_t strideBe,
                      float* __restrict__ out,
                      const float* __restrict__ gsig,
                      int K, int Mfixed,
                      const int* __restrict__ cnt,
                      const int* __restrict__ baseOff,
                      const int* __restrict__ toklist,
                      const float* __restrict__ wlist) {
  const int e = blockIdx.z;
  const int rowBlk = blockIdx.y, colBlk = blockIdx.x;
  int M;
  const bf16_t* A;
  if constexpr (EXPERT) {
    M = cnt[e];
    if (rowBlk * 128 >= M) return;
    A = Abase + (size_t)baseOff[e] * K;
  } else {
    M = Mfixed;
    A = Abase;
  }
  const bf16_t* B = Bbase + (size_t)e * strideBe;

  __shared__ __align__(16) bf16_t As[128 * 64];
  __shared__ __align__(16) bf16_t Bs[128 * 64];

  const int t = threadIdx.x;
  const bf16_t* aSrc[4];
  const bf16_t* bSrc[4];
  #pragma unroll
  for (int i = 0; i < 4; ++i) {
    int r = (t >> 3) + 32 * i;
    aSrc[i] = A + (size_t)(rowBlk * 128 + r) * K + (t & 7) * 8;
    bSrc[i] = B + (size_t)(colBlk * 128 + r) * K + (t & 7) * 8;
  }

  f32x4 acc[4][4];
  #pragma unroll
  for (int a = 0; a < 4; ++a)
    #pragma unroll
    for (int b = 0; b < 4; ++b)
      acc[a][b] = (f32x4){0.f, 0.f, 0.f, 0.f};

  const int lane = t & 63;
  const int wid = t >> 6;
  const int wm = wid >> 1, wn = wid & 1;
  const int lr = lane & 15;
  const int lk = (lane >> 4) * 8;

  bf16_t* aDst = As + t * 8;
  bf16_t* bDst = Bs + t * 8;

  for (int k0 = 0; k0 < K; k0 += 64) {
    #pragma unroll
    for (int i = 0; i < 4; ++i) gl_lds16(aSrc[i], aDst + i * 2048);
    #pragma unroll
    for (int i = 0; i < 4; ++i) gl_lds16(bSrc[i], bDst + i * 2048);
    #pragma unroll
    for (int i = 0; i < 4; ++i) { aSrc[i] += 64; bSrc[i] += 64; }
    __syncthreads();
    #pragma unroll
    for (int kk = 0; kk < 64; kk += 32) {
      bf16x8v af[4], bfr[4];
      #pragma unroll
      for (int f = 0; f < 4; ++f)
        af[f] = *(const bf16x8v*)&As[(wm * 64 + f * 16 + lr) * 64 + kk + lk];
      #pragma unroll
      for (int f = 0; f < 4; ++f)
        bfr[f] = *(const bf16x8v*)&Bs[(wn * 64 + f * 16 + lr) * 64 + kk + lk];
      #pragma unroll
      for (int fm = 0; fm < 4; ++fm)
        #pragma unroll
        for (int fn = 0; fn < 4; ++fn)
          acc[fm][fn] = __builtin_amdgcn_mfma_f32_16x16x32_bf16(
              af[fm], bfr[fn], acc[fm][fn], 0, 0, 0);
    }
    __syncthreads();
  }

  const int mRem = M - rowBlk * 128;
  #pragma unroll
  for (int fm = 0; fm < 4; ++fm) {
    #pragma unroll
    for (int r = 0; r < 4; ++r) {
      const int tr = wm * 64 + fm * 16 + (lane >> 4) * 4 + r;
      if (tr < mRem) {
        int tok; float wgt;
        if constexpr (EXPERT) {
          int slot = e * 4096 + rowBlk * 128 + tr;
          tok = toklist[slot];
          wgt = wlist[slot];
        } else {
          tok = rowBlk * 128 + tr;
          wgt = gsig[tok];
        }
        float* orow = out + (size_t)tok * 1024;
        #pragma unroll
        for (int fn = 0; fn < 4; ++fn) {
          const int col = colBlk * 128 + wn * 64 + fn * 16 + lr;
          float v = acc[fm][fn][r] * wgt;
          if constexpr (EXPERT) atomicAdd(orow + col, v);
          else orow[col] = v;
        }
      }
    }
  }
}

// ---------------- workspace layout (bytes) ----------------
// h_bf     @ 0          8,388,608
// gup_bf   @ 8388608    33,554,432
// dwn_bf   @ 41943040   16,777,216
// sg_bf    @ 58720256   4,194,304
// su_bf    @ 62914560   4,194,304
// sd_bf    @ 67108864   4,194,304
// act_s    @ 71303168   16,777,216
// act_e    @ 88080384   16,777,216 (+256KB overread pad)
// gsig     @ 105119744  16,384
// cnt      @ 105136128  64
// base     @ 105136384  64
// toklist  @ 105136640  262,144
// wlist    @ 105398784  262,144     total ~105.7 MB

extern "C" void kernel_launch(void* const* d_in, const int* in_sizes, int n_in,
                              void* d_out, int out_size, void* d_ws, size_t ws_size,
                              hipStream_t stream) {
  const float* h_f32 = (const float*)d_in[0];
  const float* rw    = (const float*)d_in[1];
  const float* gup   = (const float*)d_in[2];
  const float* dwn   = (const float*)d_in[3];
  const float* sgate = (const float*)d_in[4];
  const float* sup   = (const float*)d_in[5];
  const float* sdown = (const float*)d_in[6];
  const float* segw  = (const float*)d_in[7];

  char* ws = (char*)d_ws;
  bf16_t* h_bf    = (bf16_t*)(ws + 0);
  bf16_t* gup_bf  = (bf16_t*)(ws + 8388608);
  bf16_t* dwn_bf  = (bf16_t*)(ws + 41943040);
  bf16_t* sg_bf   = (bf16_t*)(ws + 58720256);
  bf16_t* su_bf   = (bf16_t*)(ws + 62914560);
  bf16_t* sd_bf   = (bf16_t*)(ws + 67108864);
  bf16_t* act_s   = (bf16_t*)(ws + 71303168);
  bf16_t* act_e   = (bf16_t*)(ws + 88080384);
  float*  gsig    = (float*)(ws + 105119744);
  int*    cnt     = (int*)(ws + 105136128);
  int*    baseOff = (int*)(ws + 105136384);
  int*    toklist = (int*)(ws + 105136640);
  float*  wlist   = (float*)(ws + 105398784);

  float* out = (float*)d_out;
  float* aux = out + 4194304;

  hipMemsetAsync(cnt, 0, 64, stream);

  auto cvtLaunch = [&](const float* src, bf16_t* dst, int n) {
    int n4 = n / 4;
    int blocks = (n4 + 255) / 256;
    if (blocks > 2048) blocks = 2048;
    cvt_f32_bf16_kernel<<<blocks, 256, 0, stream>>>(src, dst, n4);
  };
  cvtLaunch(h_f32, h_bf, 4194304);
  cvtLaunch(gup,   gup_bf, 16777216);
  cvtLaunch(dwn,   dwn_bf, 8388608);
  cvtLaunch(sgate, sg_bf, 2097152);
  cvtLaunch(sup,   su_bf, 2097152);
  cvtLaunch(sdown, sd_bf, 2097152);

  router_kernel<<<4096, 256, 0, stream>>>(h_f32, rw, segw, gsig, cnt, toklist, wlist);
  finalize_router_kernel<<<1, 64, 0, stream>>>(cnt, baseOff, aux);

  // shared expert gate/up -> act_s[4096][2048]
  gateup_gemm_kernel<false><<<dim3(32, 32, 1), 256, 0, stream>>>(
      h_bf, sg_bf, su_bf, (size_t)0, act_s, 2048, 1024, 4096,
      nullptr, nullptr, nullptr);
  // routed experts gate/up -> act_e (compact)[<=16384][512]
  gateup_gemm_kernel<true><<<dim3(8, 32, 16), 256, 0, stream>>>(
      h_bf, gup_bf, gup_bf + 512 * 1024, (size_t)1024 * 1024, act_e, 512, 1024, 0,
      cnt, baseOff, toklist);
  // shared down: out = sigmoid(h@seg) * act_s @ sdown^T  (plain store)
  down_gemm_kernel<false><<<dim3(8, 32, 1), 256, 0, stream>>>(
      act_s, sd_bf, (size_t)0, out, gsig, 2048, 4096,
      nullptr, nullptr, nullptr, nullptr);
  // expert down: out += w_topk * act_e @ down^T  (atomic scatter)
  down_gemm_kernel<true><<<dim3(8, 32, 16), 256, 0, stream>>>(
      act_e, dwn_bf, (size_t)1024 * 512, out, nullptr, 512, 0,
      cnt, baseOff, toklist, wlist);
}

// Round 2
// 508.985 us; speedup vs baseline: 1.2503x; 1.2503x over previous
//
#include <hip/hip_runtime.h>

typedef __bf16 bf16_t;
typedef bf16_t bf16x4v __attribute__((ext_vector_type(4)));
typedef bf16_t bf16x8v __attribute__((ext_vector_type(8)));
typedef float f32x4 __attribute__((ext_vector_type(4)));

// async global->LDS, 16B per lane (guide §5: dest = wave-uniform base + lane*16)
__device__ __forceinline__ void gl_lds16(const void* g, void* l) {
  __builtin_amdgcn_global_load_lds((__attribute__((address_space(1))) void*)g,
                                   (__attribute__((address_space(3))) void*)l,
                                   16, 0, 0);
}

__device__ __forceinline__ float fast_silu(float x) {
  return x / (1.f + __expf(-x));
}

// ---------------- f32 -> bf16 conversion (vectorized, grid-stride) ----------------
__global__ void cvt_f32_bf16_kernel(const float* __restrict__ in,
                                    bf16_t* __restrict__ out, int n4) {
  int i = blockIdx.x * blockDim.x + threadIdx.x;
  const int stride = gridDim.x * blockDim.x;
  const float4* in4 = (const float4*)in;
  bf16x4v* out4 = (bf16x4v*)out;
  for (; i < n4; i += stride) {
    float4 v = in4[i];
    bf16x4v o;
    o[0] = (bf16_t)v.x; o[1] = (bf16_t)v.y; o[2] = (bf16_t)v.z; o[3] = (bf16_t)v.w;
    out4[i] = o;
  }
}

// ---------------- R1: per-token logits + top-4 + shared gate (atomic-free) --------
// 16 lanes per token: lane e owns expert e's logit. f32 math so selection
// exactly matches the reference top_k (tie-break: lowest index).
__global__ __launch_bounds__(256)
void router_topk_kernel(const float* __restrict__ h, const float* __restrict__ rw,
                        const float* __restrict__ segw, float* __restrict__ gsig,
                        int* __restrict__ tokTopI, float* __restrict__ tokTopW) {
  const int t = threadIdx.x;
  const int lane = t & 63;
  const int wid = t >> 6;
  const int grp = lane >> 4;   // token slot within wave (4 tokens/wave)
  const int e = lane & 15;     // expert owned by this lane
  const int tok = blockIdx.x * 16 + wid * 4 + grp;

  const float4* h4 = (const float4*)(h + (size_t)tok * 1024);
  const float4* rw4 = (const float4*)(rw + (size_t)e * 1024);
  const float4* sg4 = (const float4*)segw;

  float s = 0.f, ss = 0.f;
  #pragma unroll 8
  for (int c = 0; c < 256; ++c) {
    float4 hv = h4[c];
    float4 wv = rw4[c];
    s += hv.x * wv.x + hv.y * wv.y + hv.z * wv.z + hv.w * wv.w;
    if ((c & 15) == e) {  // 1/16 stripe of the shared-gate dot per lane
      float4 gv = sg4[c];
      ss += hv.x * gv.x + hv.y * gv.y + hv.z * gv.z + hv.w * gv.w;
    }
  }
  // sum shared-gate partials over the 16-lane group
  #pragma unroll
  for (int m = 1; m <= 8; m <<= 1) ss += __shfl_xor(ss, m);
  // softmax (denominator cancels after top-k renorm; only need exp(logit-max))
  float mx = s;
  #pragma unroll
  for (int m = 1; m <= 8; m <<= 1) mx = fmaxf(mx, __shfl_xor(mx, m));
  float p = expf(s - mx);

  float pc = p;
  float tsum = 0.f;
  float myw = 0.f; int myi = 0;
  #pragma unroll
  for (int r = 0; r < 4; ++r) {
    float v = pc; int idx = e;
    #pragma unroll
    for (int m = 1; m <= 8; m <<= 1) {
      float ov = __shfl_xor(v, m); int oi = __shfl_xor(idx, m);
      if (ov > v || (ov == v && oi < idx)) { v = ov; idx = oi; }
    }
    tsum += v;
    if (e == r) { myi = idx; myw = v; }   // lane r records round-r winner
    if (e == idx) pc = -1.f;              // remove winner
  }
  if (e < 4) {
    tokTopI[tok * 4 + e] = myi;
    tokTopW[tok * 4 + e] = myw / tsum;
  }
  if (e == 0) gsig[tok] = 1.f / (1.f + expf(-ss));
}

// ---------------- R2: per-expert compact lists via block prefix scan --------------
// Block e scans all 16384 (token,k) assignments; zero atomics, deterministic.
__global__ __launch_bounds__(256)
void build_lists_kernel(const int* __restrict__ tokTopI,
                        const float* __restrict__ tokTopW,
                        int* __restrict__ cnt, int* __restrict__ toklist,
                        float* __restrict__ wlist) {
  const int e = blockIdx.x;
  const int t = threadIdx.x;
  const int lane = t & 63;
  const int wid = t >> 6;
  __shared__ int base;
  __shared__ int wsum[4];
  if (t == 0) base = 0;
  __syncthreads();

  for (int chunk = 0; chunk < 16; ++chunk) {
    const int i0 = chunk * 1024 + t * 4;
    int4 ti = *(const int4*)&tokTopI[i0];
    const bool f0 = ti.x == e, f1 = ti.y == e, f2 = ti.z == e, f3 = ti.w == e;
    const int c = (int)f0 + (int)f1 + (int)f2 + (int)f3;
    int inc = c;
    #pragma unroll
    for (int m = 1; m <= 32; m <<= 1) {
      int o = __shfl_up(inc, m);
      if (lane >= m) inc += o;
    }
    const int lanePre = inc - c;
    if (lane == 63) wsum[wid] = inc;
    __syncthreads();
    int wavePre = 0;
    #pragma unroll
    for (int w = 0; w < 4; ++w) if (w < wid) wavePre += wsum[w];
    const int total = wsum[0] + wsum[1] + wsum[2] + wsum[3];
    int pos = base + wavePre + lanePre;
    __syncthreads();                 // all threads have read base & wsum
    if (t == 0) base += total;
    float4 tw = *(const float4*)&tokTopW[i0];
    if (f0) { toklist[e * 4096 + pos] = i0 >> 2;       wlist[e * 4096 + pos] = tw.x; pos++; }
    if (f1) { toklist[e * 4096 + pos] = (i0 + 1) >> 2; wlist[e * 4096 + pos] = tw.y; pos++; }
    if (f2) { toklist[e * 4096 + pos] = (i0 + 2) >> 2; wlist[e * 4096 + pos] = tw.z; pos++; }
    if (f3) { toklist[e * 4096 + pos] = (i0 + 3) >> 2; wlist[e * 4096 + pos] = tw.w; pos++; }
  }
  __syncthreads();
  if (t == 0) cnt[e] = base;
}

// prefix over 16 counts + constant aux loss (== E exactly: both fractions sum to 1)
__global__ void finalize_router_kernel(const int* __restrict__ cnt,
                                       int* __restrict__ baseOff,
                                       float* __restrict__ aux) {
  if (threadIdx.x == 0 && blockIdx.x == 0) {
    int s = 0;
    for (int e = 0; e < 16; ++e) { baseOff[e] = s; s += cnt[e]; }
    aux[0] = 16.0f;
  }
}

// ---------------- fused gate/up GEMM: act = silu(A@B1^T) * (A@B2^T) ----------------
// B tile interleaves gate(even n)/up(odd n) rows so the epilogue pairs via shfl_xor(1).
// GATHER: A rows indirected through per-expert token list (grouped GEMM).
template<bool GATHER>
__global__ __launch_bounds__(256, 2)
void gateup_gemm_kernel(const bf16_t* __restrict__ A,
                        const bf16_t* __restrict__ B1,
                        const bf16_t* __restrict__ B2,
                        size_t strideBe,
                        bf16_t* __restrict__ actOut, int ldAct,
                        int K, int Mfixed,
                        const int* __restrict__ cnt,
                        const int* __restrict__ baseOff,
                        const int* __restrict__ toklist) {
  const int e = blockIdx.z;
  const int rowBlk = blockIdx.y, colBlk = blockIdx.x;
  int M, actRowBase;
  if constexpr (GATHER) {
    M = cnt[e];
    if (rowBlk * 128 >= M) return;
    actRowBase = baseOff[e] + rowBlk * 128;
  } else {
    M = Mfixed;
    actRowBase = rowBlk * 128;
  }
  const bf16_t* b1 = B1 + (size_t)e * strideBe;
  const bf16_t* b2 = B2 + (size_t)e * strideBe;

  __shared__ __align__(16) bf16_t As[128 * 64];
  __shared__ __align__(16) bf16_t Bs[128 * 64];

  const int t = threadIdx.x;

  const bf16_t* aSrc[4];
  const bf16_t* bSrc[4];
  #pragma unroll
  for (int i = 0; i < 4; ++i) {
    int r = (t >> 3) + 32 * i;  // tile row 0..127
    int grow;
    if constexpr (GATHER) {
      int rr = rowBlk * 128 + r;
      grow = (rr < M) ? toklist[e * 4096 + rr] : 0;
    } else {
      grow = rowBlk * 128 + r;
    }
    aSrc[i] = A + (size_t)grow * K + (t & 7) * 8;
    int j = colBlk * 64 + (r >> 1);
    bSrc[i] = ((r & 1) ? b2 : b1) + (size_t)j * K + (t & 7) * 8;
  }

  f32x4 acc[4][4];
  #pragma unroll
  for (int a = 0; a < 4; ++a)
    #pragma unroll
    for (int b = 0; b < 4; ++b)
      acc[a][b] = (f32x4){0.f, 0.f, 0.f, 0.f};

  const int lane = t & 63;
  const int wid = t >> 6;
  const int wm = wid >> 1, wn = wid & 1;
  const int lr = lane & 15;
  const int lk = (lane >> 4) * 8;

  bf16_t* aDst = As + t * 8;
  bf16_t* bDst = Bs + t * 8;

  for (int k0 = 0; k0 < K; k0 += 64) {
    #pragma unroll
    for (int i = 0; i < 4; ++i) gl_lds16(aSrc[i], aDst + i * 2048);
    #pragma unroll
    for (int i = 0; i < 4; ++i) gl_lds16(bSrc[i], bDst + i * 2048);
    #pragma unroll
    for (int i = 0; i < 4; ++i) { aSrc[i] += 64; bSrc[i] += 64; }
    __syncthreads();
    #pragma unroll
    for (int kk = 0; kk < 64; kk += 32) {
      bf16x8v af[4], bfr[4];
      #pragma unroll
      for (int f = 0; f < 4; ++f)
        af[f] = *(const bf16x8v*)&As[(wm * 64 + f * 16 + lr) * 64 + kk + lk];
      #pragma unroll
      for (int f = 0; f < 4; ++f)
        bfr[f] = *(const bf16x8v*)&Bs[(wn * 64 + f * 16 + lr) * 64 + kk + lk];
      #pragma unroll
      for (int fm = 0; fm < 4; ++fm)
        #pragma unroll
        for (int fn = 0; fn < 4; ++fn)
          acc[fm][fn] = __builtin_amdgcn_mfma_f32_16x16x32_bf16(
              af[fm], bfr[fn], acc[fm][fn], 0, 0, 0);
    }
    __syncthreads();
  }

  // epilogue: pair gate (even n) with up (odd n) via lane^1, write silu(g)*u
  const int mRem = M - rowBlk * 128;
  #pragma unroll
  for (int fm = 0; fm < 4; ++fm) {
    #pragma unroll
    for (int fn = 0; fn < 4; ++fn) {
      const int nloc = wn * 64 + fn * 16 + lr;
      const int j = colBlk * 64 + (nloc >> 1);
      const bool even = (nloc & 1) == 0;
      #pragma unroll
      for (int r = 0; r < 4; ++r) {
        float mine = acc[fm][fn][r];
        float other = __shfl_xor(mine, 1);
        float gate = even ? mine : other;
        float up = even ? other : mine;
        float act = fast_silu(gate) * up;
        int tr = wm * 64 + fm * 16 + (lane >> 4) * 4 + r;
        if (even && tr < mRem)
          actOut[(size_t)(actRowBase + tr) * ldAct + j] = (bf16_t)act;
      }
    }
  }
}

// ---------------- down GEMM: out (+)= scale * (A @ B^T) ----------------
// EXPERT: scatter rows to tokens with atomicAdd * top-k weight.
// else:   direct store * sigmoid gate (runs first, so adds are ordered after).
template<bool EXPERT>
__global__ __launch_bounds__(256, 2)
void down_gemm_kernel(const bf16_t* __restrict__ Abase,
                      const bf16_t* __restrict__ Bbase,
                      size_t strideBe,
                      float* __restrict__ out,
                      const float* __restrict__ gsig,
                      int K, int Mfixed,
                      const int* __restrict__ cnt,
                      const int* __restrict__ baseOff,
                      const int* __restrict__ toklist,
                      const float* __restrict__ wlist) {
  const int e = blockIdx.z;
  const int rowBlk = blockIdx.y, colBlk = blockIdx.x;
  int M;
  const bf16_t* A;
  if constexpr (EXPERT) {
    M = cnt[e];
    if (rowBlk * 128 >= M) return;
    A = Abase + (size_t)baseOff[e] * K;
  } else {
    M = Mfixed;
    A = Abase;
  }
  const bf16_t* B = Bbase + (size_t)e * strideBe;

  __shared__ __align__(16) bf16_t As[128 * 64];
  __shared__ __align__(16) bf16_t Bs[128 * 64];

  const int t = threadIdx.x;
  const bf16_t* aSrc[4];
  const bf16_t* bSrc[4];
  #pragma unroll
  for (int i = 0; i < 4; ++i) {
    int r = (t >> 3) + 32 * i;
    aSrc[i] = A + (size_t)(rowBlk * 128 + r) * K + (t & 7) * 8;
    bSrc[i] = B + (size_t)(colBlk * 128 + r) * K + (t & 7) * 8;
  }

  f32x4 acc[4][4];
  #pragma unroll
  for (int a = 0; a < 4; ++a)
    #pragma unroll
    for (int b = 0; b < 4; ++b)
      acc[a][b] = (f32x4){0.f, 0.f, 0.f, 0.f};

  const int lane = t & 63;
  const int wid = t >> 6;
  const int wm = wid >> 1, wn = wid & 1;
  const int lr = lane & 15;
  const int lk = (lane >> 4) * 8;

  bf16_t* aDst = As + t * 8;
  bf16_t* bDst = Bs + t * 8;

  for (int k0 = 0; k0 < K; k0 += 64) {
    #pragma unroll
    for (int i = 0; i < 4; ++i) gl_lds16(aSrc[i], aDst + i * 2048);
    #pragma unroll
    for (int i = 0; i < 4; ++i) gl_lds16(bSrc[i], bDst + i * 2048);
    #pragma unroll
    for (int i = 0; i < 4; ++i) { aSrc[i] += 64; bSrc[i] += 64; }
    __syncthreads();
    #pragma unroll
    for (int kk = 0; kk < 64; kk += 32) {
      bf16x8v af[4], bfr[4];
      #pragma unroll
      for (int f = 0; f < 4; ++f)
        af[f] = *(const bf16x8v*)&As[(wm * 64 + f * 16 + lr) * 64 + kk + lk];
      #pragma unroll
      for (int f = 0; f < 4; ++f)
        bfr[f] = *(const bf16x8v*)&Bs[(wn * 64 + f * 16 + lr) * 64 + kk + lk];
      #pragma unroll
      for (int fm = 0; fm < 4; ++fm)
        #pragma unroll
        for (int fn = 0; fn < 4; ++fn)
          acc[fm][fn] = __builtin_amdgcn_mfma_f32_16x16x32_bf16(
              af[fm], bfr[fn], acc[fm][fn], 0, 0, 0);
    }
    __syncthreads();
  }

  const int mRem = M - rowBlk * 128;
  #pragma unroll
  for (int fm = 0; fm < 4; ++fm) {
    #pragma unroll
    for (int r = 0; r < 4; ++r) {
      const int tr = wm * 64 + fm * 16 + (lane >> 4) * 4 + r;
      if (tr < mRem) {
        int tok; float wgt;
        if constexpr (EXPERT) {
          int slot = e * 4096 + rowBlk * 128 + tr;
          tok = toklist[slot];
          wgt = wlist[slot];
        } else {
          tok = rowBlk * 128 + tr;
          wgt = gsig[tok];
        }
        float* orow = out + (size_t)tok * 1024;
        #pragma unroll
        for (int fn = 0; fn < 4; ++fn) {
          const int col = colBlk * 128 + wn * 64 + fn * 16 + lr;
          float v = acc[fm][fn][r] * wgt;
          if constexpr (EXPERT) atomicAdd(orow + col, v);
          else orow[col] = v;
        }
      }
    }
  }
}

// ---------------- workspace layout (bytes) ----------------
// h_bf     @ 0          8,388,608
// gup_bf   @ 8388608    33,554,432
// dwn_bf   @ 41943040   16,777,216
// sg_bf    @ 58720256   4,194,304
// su_bf    @ 62914560   4,194,304
// sd_bf    @ 67108864   4,194,304
// act_s    @ 71303168   16,777,216
// act_e    @ 88080384   16,777,216
// gsig     @ 105119744  16,384
// cnt      @ 105136128  64
// base     @ 105136384  64
// toklist  @ 105136640  262,144
// wlist    @ 105398784  262,144
// tokTopI  @ 105660928  65,536
// tokTopW  @ 105726464  65,536     total ~105.8 MB

extern "C" void kernel_launch(void* const* d_in, const int* in_sizes, int n_in,
                              void* d_out, int out_size, void* d_ws, size_t ws_size,
                              hipStream_t stream) {
  const float* h_f32 = (const float*)d_in[0];
  const float* rw    = (const float*)d_in[1];
  const float* gup   = (const float*)d_in[2];
  const float* dwn   = (const float*)d_in[3];
  const float* sgate = (const float*)d_in[4];
  const float* sup   = (const float*)d_in[5];
  const float* sdown = (const float*)d_in[6];
  const float* segw  = (const float*)d_in[7];

  char* ws = (char*)d_ws;
  bf16_t* h_bf    = (bf16_t*)(ws + 0);
  bf16_t* gup_bf  = (bf16_t*)(ws + 8388608);
  bf16_t* dwn_bf  = (bf16_t*)(ws + 41943040);
  bf16_t* sg_bf   = (bf16_t*)(ws + 58720256);
  bf16_t* su_bf   = (bf16_t*)(ws + 62914560);
  bf16_t* sd_bf   = (bf16_t*)(ws + 67108864);
  bf16_t* act_s   = (bf16_t*)(ws + 71303168);
  bf16_t* act_e   = (bf16_t*)(ws + 88080384);
  float*  gsig    = (float*)(ws + 105119744);
  int*    cnt     = (int*)(ws + 105136128);
  int*    baseOff = (int*)(ws + 105136384);
  int*    toklist = (int*)(ws + 105136640);
  float*  wlist   = (float*)(ws + 105398784);
  int*    tokTopI = (int*)(ws + 105660928);
  float*  tokTopW = (float*)(ws + 105726464);

  float* out = (float*)d_out;
  float* aux = out + 4194304;

  auto cvtLaunch = [&](const float* src, bf16_t* dst, int n) {
    int n4 = n / 4;
    int blocks = (n4 + 255) / 256;
    if (blocks > 2048) blocks = 2048;
    cvt_f32_bf16_kernel<<<blocks, 256, 0, stream>>>(src, dst, n4);
  };
  cvtLaunch(h_f32, h_bf, 4194304);
  cvtLaunch(gup,   gup_bf, 16777216);
  cvtLaunch(dwn,   dwn_bf, 8388608);
  cvtLaunch(sgate, sg_bf, 2097152);
  cvtLaunch(sup,   su_bf, 2097152);
  cvtLaunch(sdown, sd_bf, 2097152);

  router_topk_kernel<<<256, 256, 0, stream>>>(h_f32, rw, segw, gsig, tokTopI, tokTopW);
  build_lists_kernel<<<16, 256, 0, stream>>>(tokTopI, tokTopW, cnt, toklist, wlist);
  finalize_router_kernel<<<1, 64, 0, stream>>>(cnt, baseOff, aux);

  // shared expert gate/up -> act_s[4096][2048]
  gateup_gemm_kernel<false><<<dim3(32, 32, 1), 256, 0, stream>>>(
      h_bf, sg_bf, su_bf, (size_t)0, act_s, 2048, 1024, 4096,
      nullptr, nullptr, nullptr);
  // routed experts gate/up -> act_e (compact)[<=16384][512]
  gateup_gemm_kernel<true><<<dim3(8, 32, 16), 256, 0, stream>>>(
      h_bf, gup_bf, gup_bf + 512 * 1024, (size_t)1024 * 1024, act_e, 512, 1024, 0,
      cnt, baseOff, toklist);
  // shared down: out = sigmoid(h@seg) * act_s @ sdown^T  (plain store)
  down_gemm_kernel<false><<<dim3(8, 32, 1), 256, 0, stream>>>(
      act_s, sd_bf, (size_t)0, out, gsig, 2048, 4096,
      nullptr, nullptr, nullptr, nullptr);
  // expert down: out += w_topk * act_e @ down^T  (atomic scatter)
  down_gemm_kernel<true><<<dim3(8, 32, 16), 256, 0, stream>>>(
      act_e, dwn_bf, (size_t)1024 * 512, out, nullptr, 512, 0,
      cnt, baseOff, toklist, wlist);
}

// Round 4
// 459.903 us; speedup vs baseline: 1.3837x; 1.1067x over previous
//
#include <hip/hip_runtime.h>

typedef __bf16 bf16_t;
typedef bf16_t bf16x4v __attribute__((ext_vector_type(4)));
typedef bf16_t bf16x8v __attribute__((ext_vector_type(8)));
typedef float f32x4 __attribute__((ext_vector_type(4)));

// async global->LDS, 16B per lane (dest = wave-uniform base + lane*16)
__device__ __forceinline__ void gl_lds16(const void* g, void* l) {
  __builtin_amdgcn_global_load_lds((__attribute__((address_space(1))) void*)g,
                                   (__attribute__((address_space(3))) void*)l,
                                   16, 0, 0);
}

__device__ __forceinline__ float fast_silu(float x) {
  return x / (1.f + __expf(-x));
}

// ---------------- f32 -> bf16 conversion (vectorized, grid-stride) ----------------
__global__ void cvt_f32_bf16_kernel(const float* __restrict__ in,
                                    bf16_t* __restrict__ out, int n4) {
  int i = blockIdx.x * blockDim.x + threadIdx.x;
  const int stride = gridDim.x * blockDim.x;
  const float4* in4 = (const float4*)in;
  bf16x4v* out4 = (bf16x4v*)out;
  for (; i < n4; i += stride) {
    float4 v = in4[i];
    bf16x4v o;
    o[0] = (bf16_t)v.x; o[1] = (bf16_t)v.y; o[2] = (bf16_t)v.z; o[3] = (bf16_t)v.w;
    out4[i] = o;
  }
}

// ---------------- R1: per-token logits + top-4 + shared gate (atomic-free) --------
__global__ __launch_bounds__(256)
void router_topk_kernel(const float* __restrict__ h, const float* __restrict__ rw,
                        const float* __restrict__ segw, float* __restrict__ gsig,
                        int* __restrict__ tokTopI, float* __restrict__ tokTopW) {
  const int t = threadIdx.x;
  const int lane = t & 63;
  const int wid = t >> 6;
  const int grp = lane >> 4;
  const int e = lane & 15;
  const int tok = blockIdx.x * 16 + wid * 4 + grp;

  const float4* h4 = (const float4*)(h + (size_t)tok * 1024);
  const float4* rw4 = (const float4*)(rw + (size_t)e * 1024);
  const float4* sg4 = (const float4*)segw;

  float s = 0.f, ss = 0.f;
  #pragma unroll 8
  for (int c = 0; c < 256; ++c) {
    float4 hv = h4[c];
    float4 wv = rw4[c];
    s += hv.x * wv.x + hv.y * wv.y + hv.z * wv.z + hv.w * wv.w;
    if ((c & 15) == e) {
      float4 gv = sg4[c];
      ss += hv.x * gv.x + hv.y * gv.y + hv.z * gv.z + hv.w * gv.w;
    }
  }
  #pragma unroll
  for (int m = 1; m <= 8; m <<= 1) ss += __shfl_xor(ss, m);
  float mx = s;
  #pragma unroll
  for (int m = 1; m <= 8; m <<= 1) mx = fmaxf(mx, __shfl_xor(mx, m));
  float p = expf(s - mx);

  float pc = p;
  float tsum = 0.f;
  float myw = 0.f; int myi = 0;
  #pragma unroll
  for (int r = 0; r < 4; ++r) {
    float v = pc; int idx = e;
    #pragma unroll
    for (int m = 1; m <= 8; m <<= 1) {
      float ov = __shfl_xor(v, m); int oi = __shfl_xor(idx, m);
      if (ov > v || (ov == v && oi < idx)) { v = ov; idx = oi; }
    }
    tsum += v;
    if (e == r) { myi = idx; myw = v; }
    if (e == idx) pc = -1.f;
  }
  if (e < 4) {
    tokTopI[tok * 4 + e] = myi;
    tokTopW[tok * 4 + e] = myw / tsum;
  }
  if (e == 0) gsig[tok] = 1.f / (1.f + expf(-ss));
}

// ---------------- R2: per-expert compact lists + per-assignment positions ---------
__global__ __launch_bounds__(256)
void build_lists_kernel(const int* __restrict__ tokTopI,
                        const float* __restrict__ tokTopW,
                        int* __restrict__ cnt, int* __restrict__ toklist,
                        float* __restrict__ wlist, int* __restrict__ posOf) {
  const int e = blockIdx.x;
  const int t = threadIdx.x;
  const int lane = t & 63;
  const int wid = t >> 6;
  __shared__ int base;
  __shared__ int wsum[4];
  if (t == 0) base = 0;
  __syncthreads();

  for (int chunk = 0; chunk < 16; ++chunk) {
    const int i0 = chunk * 1024 + t * 4;
    int4 ti = *(const int4*)&tokTopI[i0];
    const bool f0 = ti.x == e, f1 = ti.y == e, f2 = ti.z == e, f3 = ti.w == e;
    const int c = (int)f0 + (int)f1 + (int)f2 + (int)f3;
    int inc = c;
    #pragma unroll
    for (int m = 1; m <= 32; m <<= 1) {
      int o = __shfl_up(inc, m);
      if (lane >= m) inc += o;
    }
    const int lanePre = inc - c;
    if (lane == 63) wsum[wid] = inc;
    __syncthreads();
    int wavePre = 0;
    #pragma unroll
    for (int w = 0; w < 4; ++w) if (w < wid) wavePre += wsum[w];
    const int total = wsum[0] + wsum[1] + wsum[2] + wsum[3];
    int pos = base + wavePre + lanePre;
    __syncthreads();                 // all threads have read base & wsum
    if (t == 0) base += total;
    float4 tw = *(const float4*)&tokTopW[i0];
    if (f0) { toklist[e * 4096 + pos] = i0 >> 2;       wlist[e * 4096 + pos] = tw.x; posOf[i0]     = pos; pos++; }
    if (f1) { toklist[e * 4096 + pos] = (i0 + 1) >> 2; wlist[e * 4096 + pos] = tw.y; posOf[i0 + 1] = pos; pos++; }
    if (f2) { toklist[e * 4096 + pos] = (i0 + 2) >> 2; wlist[e * 4096 + pos] = tw.z; posOf[i0 + 2] = pos; pos++; }
    if (f3) { toklist[e * 4096 + pos] = (i0 + 3) >> 2; wlist[e * 4096 + pos] = tw.w; posOf[i0 + 3] = pos; pos++; }
  }
  __syncthreads();
  if (t == 0) cnt[e] = base;
}

__global__ void finalize_router_kernel(const int* __restrict__ cnt,
                                       int* __restrict__ baseOff,
                                       float* __restrict__ aux) {
  if (threadIdx.x == 0 && blockIdx.x == 0) {
    int s = 0;
    for (int e = 0; e < 16; ++e) { baseOff[e] = s; s += cnt[e]; }
    aux[0] = 16.0f;  // both load-balance fractions sum to 1 exactly
  }
}

// ---------------- fused gate/up GEMM: act = silu(A@B1^T) * (A@B2^T) ----------------
// LDS bank-conflict fix (T2 + rule #21): LDS dest stays linear; the global SOURCE
// column chunk is pre-swizzled (c ^= row&7), and ds_read applies the same XOR.
template<bool GATHER>
__global__ __launch_bounds__(256, 4)
void gateup_gemm_kernel(const bf16_t* __restrict__ A,
                        const bf16_t* __restrict__ B1,
                        const bf16_t* __restrict__ B2,
                        size_t strideBe,
                        bf16_t* __restrict__ actOut, int ldAct,
                        int K, int Mfixed,
                        const int* __restrict__ cnt,
                        const int* __restrict__ baseOff,
                        const int* __restrict__ toklist) {
  const int e = blockIdx.z;
  const int rowBlk = blockIdx.y, colBlk = blockIdx.x;
  int M, actRowBase;
  if constexpr (GATHER) {
    M = cnt[e];
    if (rowBlk * 128 >= M) return;
    actRowBase = baseOff[e] + rowBlk * 128;
  } else {
    M = Mfixed;
    actRowBase = rowBlk * 128;
  }
  const bf16_t* b1 = B1 + (size_t)e * strideBe;
  const bf16_t* b2 = B2 + (size_t)e * strideBe;

  __shared__ __align__(16) bf16_t As[128 * 64];
  __shared__ __align__(16) bf16_t Bs[128 * 64];

  const int t = threadIdx.x;
  // swizzled source column: chunk (t&7) XOR tile-row&7  (16B granules)
  const int sc = (((t & 7) ^ ((t >> 3) & 7))) * 8;

  const bf16_t* aSrc[4];
  const bf16_t* bSrc[4];
  #pragma unroll
  for (int i = 0; i < 4; ++i) {
    int r = (t >> 3) + 32 * i;  // tile row 0..127 (r&7 invariant in i)
    int grow;
    if constexpr (GATHER) {
      int rr = rowBlk * 128 + r;
      grow = (rr < M) ? toklist[e * 4096 + rr] : 0;
    } else {
      grow = rowBlk * 128 + r;
    }
    aSrc[i] = A + (size_t)grow * K + sc;
    int j = colBlk * 64 + (r >> 1);
    bSrc[i] = ((r & 1) ? b2 : b1) + (size_t)j * K + sc;
  }

  f32x4 acc[4][4];
  #pragma unroll
  for (int a = 0; a < 4; ++a)
    #pragma unroll
    for (int b = 0; b < 4; ++b)
      acc[a][b] = (f32x4){0.f, 0.f, 0.f, 0.f};

  const int lane = t & 63;
  const int wid = t >> 6;
  const int wm = wid >> 1, wn = wid & 1;
  const int lr = lane & 15;
  const int lk = (lane >> 4) * 8;

  bf16_t* aDst = As + t * 8;
  bf16_t* bDst = Bs + t * 8;

  for (int k0 = 0; k0 < K; k0 += 64) {
    #pragma unroll
    for (int i = 0; i < 4; ++i) gl_lds16(aSrc[i], aDst + i * 2048);
    #pragma unroll
    for (int i = 0; i < 4; ++i) gl_lds16(bSrc[i], bDst + i * 2048);
    #pragma unroll
    for (int i = 0; i < 4; ++i) { aSrc[i] += 64; bSrc[i] += 64; }
    __syncthreads();
    #pragma unroll
    for (int kk = 0; kk < 64; kk += 32) {
      bf16x8v af[4], bfr[4];
      #pragma unroll
      for (int f = 0; f < 4; ++f) {
        const int row = wm * 64 + f * 16 + lr;
        af[f] = *(const bf16x8v*)&As[row * 64 + ((kk + lk) ^ ((row & 7) << 3))];
      }
      #pragma unroll
      for (int f = 0; f < 4; ++f) {
        const int row = wn * 64 + f * 16 + lr;
        bfr[f] = *(const bf16x8v*)&Bs[row * 64 + ((kk + lk) ^ ((row & 7) << 3))];
      }
      #pragma unroll
      for (int fm = 0; fm < 4; ++fm)
        #pragma unroll
        for (int fn = 0; fn < 4; ++fn)
          acc[fm][fn] = __builtin_amdgcn_mfma_f32_16x16x32_bf16(
              af[fm], bfr[fn], acc[fm][fn], 0, 0, 0);
    }
    __syncthreads();
  }

  // epilogue: pair gate (even n) with up (odd n) via lane^1, write silu(g)*u
  const int mRem = M - rowBlk * 128;
  #pragma unroll
  for (int fm = 0; fm < 4; ++fm) {
    #pragma unroll
    for (int fn = 0; fn < 4; ++fn) {
      const int nloc = wn * 64 + fn * 16 + lr;
      const int j = colBlk * 64 + (nloc >> 1);
      const bool even = (nloc & 1) == 0;
      #pragma unroll
      for (int r = 0; r < 4; ++r) {
        float mine = acc[fm][fn][r];
        float other = __shfl_xor(mine, 1);
        float gate = even ? mine : other;
        float up = even ? other : mine;
        float act = fast_silu(gate) * up;
        int tr = wm * 64 + fm * 16 + (lane >> 4) * 4 + r;
        if (even && tr < mRem)
          actOut[(size_t)(actRowBase + tr) * ldAct + j] = (bf16_t)act;
      }
    }
  }
}

// ---------------- down GEMM: C = scale * (A @ B^T) ----------------
// EXPERT: plain bf16 stores (weights pre-applied) into compact slot-order buffer;
//         a separate combine kernel gathers per token. No atomics.
// else:   f32 stores of sigmoid(gate)*acc directly into out.
template<bool EXPERT>
__global__ __launch_bounds__(256, 4)
void down_gemm_kernel(const bf16_t* __restrict__ Abase,
                      const bf16_t* __restrict__ Bbase,
                      size_t strideBe,
                      float* __restrict__ outF,
                      bf16_t* __restrict__ outB,
                      const float* __restrict__ gsig,
                      int K, int Mfixed,
                      const int* __restrict__ cnt,
                      const int* __restrict__ baseOff,
                      const float* __restrict__ wlist) {
  const int e = blockIdx.z;
  const int rowBlk = blockIdx.y, colBlk = blockIdx.x;
  int M, aRowBase;
  const bf16_t* A;
  if constexpr (EXPERT) {
    M = cnt[e];
    if (rowBlk * 128 >= M) return;
    aRowBase = baseOff[e] + rowBlk * 128;
    A = Abase + (size_t)baseOff[e] * K;
  } else {
    M = Mfixed;
    aRowBase = rowBlk * 128;
    A = Abase;
  }
  const bf16_t* B = Bbase + (size_t)e * strideBe;

  __shared__ __align__(16) bf16_t As[128 * 64];
  __shared__ __align__(16) bf16_t Bs[128 * 64];

  const int t = threadIdx.x;
  const int sc = (((t & 7) ^ ((t >> 3) & 7))) * 8;
  const bf16_t* aSrc[4];
  const bf16_t* bSrc[4];
  #pragma unroll
  for (int i = 0; i < 4; ++i) {
    int r = (t >> 3) + 32 * i;
    aSrc[i] = A + (size_t)(rowBlk * 128 + r) * K + sc;
    bSrc[i] = B + (size_t)(colBlk * 128 + r) * K + sc;
  }

  f32x4 acc[4][4];
  #pragma unroll
  for (int a = 0; a < 4; ++a)
    #pragma unroll
    for (int b = 0; b < 4; ++b)
      acc[a][b] = (f32x4){0.f, 0.f, 0.f, 0.f};

  const int lane = t & 63;
  const int wid = t >> 6;
  const int wm = wid >> 1, wn = wid & 1;
  const int lr = lane & 15;
  const int lk = (lane >> 4) * 8;

  bf16_t* aDst = As + t * 8;
  bf16_t* bDst = Bs + t * 8;

  for (int k0 = 0; k0 < K; k0 += 64) {
    #pragma unroll
    for (int i = 0; i < 4; ++i) gl_lds16(aSrc[i], aDst + i * 2048);
    #pragma unroll
    for (int i = 0; i < 4; ++i) gl_lds16(bSrc[i], bDst + i * 2048);
    #pragma unroll
    for (int i = 0; i < 4; ++i) { aSrc[i] += 64; bSrc[i] += 64; }
    __syncthreads();
    #pragma unroll
    for (int kk = 0; kk < 64; kk += 32) {
      bf16x8v af[4], bfr[4];
      #pragma unroll
      for (int f = 0; f < 4; ++f) {
        const int row = wm * 64 + f * 16 + lr;
        af[f] = *(const bf16x8v*)&As[row * 64 + ((kk + lk) ^ ((row & 7) << 3))];
      }
      #pragma unroll
      for (int f = 0; f < 4; ++f) {
        const int row = wn * 64 + f * 16 + lr;
        bfr[f] = *(const bf16x8v*)&Bs[row * 64 + ((kk + lk) ^ ((row & 7) << 3))];
      }
      #pragma unroll
      for (int fm = 0; fm < 4; ++fm)
        #pragma unroll
        for (int fn = 0; fn < 4; ++fn)
          acc[fm][fn] = __builtin_amdgcn_mfma_f32_16x16x32_bf16(
              af[fm], bfr[fn], acc[fm][fn], 0, 0, 0);
    }
    __syncthreads();
  }

  const int mRem = M - rowBlk * 128;
  #pragma unroll
  for (int fm = 0; fm < 4; ++fm) {
    #pragma unroll
    for (int r = 0; r < 4; ++r) {
      const int tr = wm * 64 + fm * 16 + (lane >> 4) * 4 + r;
      if (tr < mRem) {
        float wgt;
        if constexpr (EXPERT) wgt = wlist[e * 4096 + rowBlk * 128 + tr];
        else                  wgt = gsig[rowBlk * 128 + tr];
        #pragma unroll
        for (int fn = 0; fn < 4; ++fn) {
          const int col = colBlk * 128 + wn * 64 + fn * 16 + lr;
          float v = acc[fm][fn][r] * wgt;
          if constexpr (EXPERT)
            outB[(size_t)(aRowBase + tr) * 1024 + col] = (bf16_t)v;
          else
            outF[(size_t)(aRowBase + tr) * 1024 + col] = v;
        }
      }
    }
  }
}

// ---------------- combine: out[tok] += sum of the token's 4 expert rows ----------
__global__ __launch_bounds__(256)
void combine_kernel(const bf16_t* __restrict__ dsc,
                    const int* __restrict__ tokTopI,
                    const int* __restrict__ posOf,
                    const int* __restrict__ baseOff,
                    float* __restrict__ out) {
  const int tok = blockIdx.x;
  const int t = threadIdx.x;
  __shared__ const bf16_t* rows[4];
  if (t < 4) {
    int e = tokTopI[tok * 4 + t];
    rows[t] = dsc + (size_t)(baseOff[e] + posOf[tok * 4 + t]) * 1024;
  }
  __syncthreads();
  float4* orow = (float4*)(out + (size_t)tok * 1024);
  float4 v = orow[t];
  #pragma unroll
  for (int k = 0; k < 4; ++k) {
    bf16x4v b = *(const bf16x4v*)(rows[k] + t * 4);
    v.x += (float)b[0]; v.y += (float)b[1]; v.z += (float)b[2]; v.w += (float)b[3];
  }
  orow[t] = v;
}

// ---------------- workspace layout (bytes) ----------------
// h_bf     @ 0          8,388,608
// gup_bf   @ 8388608    33,554,432   (reused as dsc[16384*1024 bf16] after expert gateup)
// dwn_bf   @ 41943040   16,777,216
// sg_bf    @ 58720256   4,194,304
// su_bf    @ 62914560   4,194,304
// sd_bf    @ 67108864   4,194,304
// act_s    @ 71303168   16,777,216
// act_e    @ 88080384   16,777,216
// gsig     @ 105119744  16,384
// cnt      @ 105136128  64
// base     @ 105136384  64
// toklist  @ 105136640  262,144
// wlist    @ 105398784  262,144
// tokTopI  @ 105660928  65,536
// tokTopW  @ 105726464  65,536
// posOf    @ 105791744  65,536      total ~105.9 MB

extern "C" void kernel_launch(void* const* d_in, const int* in_sizes, int n_in,
                              void* d_out, int out_size, void* d_ws, size_t ws_size,
                              hipStream_t stream) {
  const float* h_f32 = (const float*)d_in[0];
  const float* rw    = (const float*)d_in[1];
  const float* gup   = (const float*)d_in[2];
  const float* dwn   = (const float*)d_in[3];
  const float* sgate = (const float*)d_in[4];
  const float* sup   = (const float*)d_in[5];
  const float* sdown = (const float*)d_in[6];
  const float* segw  = (const float*)d_in[7];

  char* ws = (char*)d_ws;
  bf16_t* h_bf    = (bf16_t*)(ws + 0);
  bf16_t* gup_bf  = (bf16_t*)(ws + 8388608);
  bf16_t* dwn_bf  = (bf16_t*)(ws + 41943040);
  bf16_t* sg_bf   = (bf16_t*)(ws + 58720256);
  bf16_t* su_bf   = (bf16_t*)(ws + 62914560);
  bf16_t* sd_bf   = (bf16_t*)(ws + 67108864);
  bf16_t* act_s   = (bf16_t*)(ws + 71303168);
  bf16_t* act_e   = (bf16_t*)(ws + 88080384);
  float*  gsig    = (float*)(ws + 105119744);
  int*    cnt     = (int*)(ws + 105136128);
  int*    baseOff = (int*)(ws + 105136384);
  int*    toklist = (int*)(ws + 105136640);
  float*  wlist   = (float*)(ws + 105398784);
  int*    tokTopI = (int*)(ws + 105660928);
  float*  tokTopW = (float*)(ws + 105726464);
  int*    posOf   = (int*)(ws + 105791744);
  bf16_t* dsc     = gup_bf;  // 32MB, safe: expert gate/up (last reader) precedes
                             // expert down (writer) in stream order

  float* out = (float*)d_out;
  float* aux = out + 4194304;

  auto cvtLaunch = [&](const float* src, bf16_t* dst, int n) {
    int n4 = n / 4;
    int blocks = (n4 + 255) / 256;
    if (blocks > 2048) blocks = 2048;
    cvt_f32_bf16_kernel<<<blocks, 256, 0, stream>>>(src, dst, n4);
  };
  cvtLaunch(h_f32, h_bf, 4194304);
  cvtLaunch(gup,   gup_bf, 16777216);
  cvtLaunch(dwn,   dwn_bf, 8388608);
  cvtLaunch(sgate, sg_bf, 2097152);
  cvtLaunch(sup,   su_bf, 2097152);
  cvtLaunch(sdown, sd_bf, 2097152);

  router_topk_kernel<<<256, 256, 0, stream>>>(h_f32, rw, segw, gsig, tokTopI, tokTopW);
  build_lists_kernel<<<16, 256, 0, stream>>>(tokTopI, tokTopW, cnt, toklist, wlist, posOf);
  finalize_router_kernel<<<1, 64, 0, stream>>>(cnt, baseOff, aux);

  // shared expert gate/up -> act_s[4096][2048]
  gateup_gemm_kernel<false><<<dim3(32, 32, 1), 256, 0, stream>>>(
      h_bf, sg_bf, su_bf, (size_t)0, act_s, 2048, 1024, 4096,
      nullptr, nullptr, nullptr);
  // routed experts gate/up -> act_e (compact)[<=16384][512]
  gateup_gemm_kernel<true><<<dim3(8, 32, 16), 256, 0, stream>>>(
      h_bf, gup_bf, gup_bf + 512 * 1024, (size_t)1024 * 1024, act_e, 512, 1024, 0,
      cnt, baseOff, toklist);
  // shared down: out = sigmoid(h@seg) * act_s @ sdown^T  (plain f32 store)
  down_gemm_kernel<false><<<dim3(8, 32, 1), 256, 0, stream>>>(
      act_s, sd_bf, (size_t)0, out, nullptr, gsig, 2048, 4096,
      nullptr, nullptr, nullptr);
  // expert down: dsc[slot] = w_topk * act_e @ down^T  (plain bf16 store, no atomics)
  down_gemm_kernel<true><<<dim3(8, 32, 16), 256, 0, stream>>>(
      act_e, dwn_bf, (size_t)1024 * 512, nullptr, dsc, nullptr, 512, 0,
      cnt, baseOff, wlist);
  // gather the 4 rows per token and add into out
  combine_kernel<<<4096, 256, 0, stream>>>(dsc, tokTopI, posOf, baseOff, out);
}